// Round 2
// baseline (382.413 us; speedup 1.0000x reference)
//
#include <hip/hip_runtime.h>
#include <hip/hip_bf16.h>

typedef unsigned short u16;
typedef short bf16x8 __attribute__((ext_vector_type(8)));
typedef float f32x4 __attribute__((ext_vector_type(4)));

#define HID 128
#define FFN 256

__device__ __forceinline__ float bf2f(u16 u){
  union { unsigned int i; float f; } v; v.i = ((unsigned int)u) << 16; return v.f;
}
__device__ __forceinline__ u16 f2bf(float f){
  union { float f; unsigned int i; } v; v.f = f;
  unsigned int x = v.i;
  unsigned int r = (x + 0x7fffu + ((x >> 16) & 1u)) >> 16;
  return (u16)r;
}

// ---------------- CSR build ----------------

__global__ __launch_bounds__(256) void count_kernel(const int* __restrict__ dst, int* __restrict__ cnt,
                                                    int E, int N){
  int e = blockIdx.x * 256 + threadIdx.x;
  if (e < E){
    int d = dst[e];
    if ((unsigned)d < (unsigned)N) atomicAdd(&cnt[d], 1);
  }
}

__global__ __launch_bounds__(256) void dinv_kernel(const int* __restrict__ cnt, float* __restrict__ dinv, int N){
  int i = blockIdx.x * 256 + threadIdx.x;
  if (i < N) dinv[i] = rsqrtf((float)cnt[i] + 2.0f);
}

__global__ __launch_bounds__(256) void scan1(const int* __restrict__ cnt, int* __restrict__ part, int N){
  __shared__ int sm[256];
  int i = blockIdx.x * 256 + threadIdx.x;
  sm[threadIdx.x] = (i < N) ? cnt[i] : 0;
  __syncthreads();
  for (int o = 128; o; o >>= 1){
    if (threadIdx.x < o) sm[threadIdx.x] += sm[threadIdx.x + o];
    __syncthreads();
  }
  if (threadIdx.x == 0) part[blockIdx.x] = sm[0];
}

__global__ void scan2(const int* __restrict__ part, int* __restrict__ parts, int* __restrict__ rp,
                      int NB, int N){
  if (threadIdx.x == 0 && blockIdx.x == 0){
    int run = 0;
    for (int b = 0; b < NB; b++){ parts[b] = run; run += part[b]; }
    rp[N] = run;
  }
}

__global__ __launch_bounds__(256) void scan3(const int* __restrict__ cnt, const int* __restrict__ parts,
                                             int* __restrict__ rp, int N){
  __shared__ int sm[256];
  int t = threadIdx.x;
  int i = blockIdx.x * 256 + t;
  int v = (i < N) ? cnt[i] : 0;
  sm[t] = v;
  __syncthreads();
  for (int o = 1; o < 256; o <<= 1){
    int add = (t >= o) ? sm[t - o] : 0;
    __syncthreads();
    sm[t] += add;
    __syncthreads();
  }
  if (i < N) rp[i] = parts[blockIdx.x] + sm[t] - v;
}

__global__ __launch_bounds__(256) void scatter_kernel(const int* __restrict__ src, const int* __restrict__ dst,
                                                      const int* __restrict__ rp, int* __restrict__ cur,
                                                      int* __restrict__ ss, int E, int N){
  int e = blockIdx.x * 256 + threadIdx.x;
  if (e < E){
    int d = dst[e];
    if ((unsigned)d < (unsigned)N){
      int p = atomicAdd(&cur[d], 1);
      ss[rp[d] + p] = src[e];
    }
  }
}

// ---------------- LayerNorm ----------------
// ln1: fp32 in [N,128] -> bf16 out.  One wave per row, 2 elems/lane.

__global__ __launch_bounds__(256) void ln1_kernel(const float* __restrict__ x, const float* __restrict__ g,
                                                  const float* __restrict__ b, u16* __restrict__ xn, int N){
  int wv = threadIdx.x >> 6, lane = threadIdx.x & 63;
  int row = blockIdx.x * 4 + wv;
  if (row >= N) return;
  float2 xv = *(const float2*)(x + (size_t)row * HID + lane * 2);
  float x0 = xv.x, x1 = xv.y;
  float s = x0 + x1, sq = x0 * x0 + x1 * x1;
  for (int o = 32; o; o >>= 1){ s += __shfl_xor(s, o, 64); sq += __shfl_xor(sq, o, 64); }
  float mu = s * (1.f / HID);
  float var = sq * (1.f / HID) - mu * mu;
  float rs = rsqrtf(var + 1e-5f);
  float2 gv = *(const float2*)(g + lane * 2);
  float2 bv = *(const float2*)(b + lane * 2);
  ushort2 ov;
  ov.x = f2bf((x0 - mu) * rs * gv.x + bv.x);
  ov.y = f2bf((x1 - mu) * rs * gv.y + bv.y);
  *(ushort2*)(xn + (size_t)row * HID + lane * 2) = ov;
}

// ln2: bf16 in [N,256] -> bf16 out.  One wave per row, 4 elems/lane.

__global__ __launch_bounds__(256) void ln2_kernel(const u16* __restrict__ h, const float* __restrict__ g,
                                                  const float* __restrict__ b, u16* __restrict__ out, int N){
  int wv = threadIdx.x >> 6, lane = threadIdx.x & 63;
  int row = blockIdx.x * 4 + wv;
  if (row >= N) return;
  ushort4 xv = *(const ushort4*)(h + (size_t)row * FFN + lane * 4);
  float x0 = bf2f(xv.x), x1 = bf2f(xv.y), x2 = bf2f(xv.z), x3 = bf2f(xv.w);
  float s = x0 + x1 + x2 + x3;
  float sq = x0 * x0 + x1 * x1 + x2 * x2 + x3 * x3;
  for (int o = 32; o; o >>= 1){ s += __shfl_xor(s, o, 64); sq += __shfl_xor(sq, o, 64); }
  float mu = s * (1.f / FFN);
  float var = sq * (1.f / FFN) - mu * mu;
  float rs = rsqrtf(var + 1e-5f);
  float4 gv = *(const float4*)(g + lane * 4);
  float4 bv = *(const float4*)(b + lane * 4);
  ushort4 ov;
  ov.x = f2bf((x0 - mu) * rs * gv.x + bv.x);
  ov.y = f2bf((x1 - mu) * rs * gv.y + bv.y);
  ov.z = f2bf((x2 - mu) * rs * gv.z + bv.z);
  ov.w = f2bf((x3 - mu) * rs * gv.w + bv.w);
  *(ushort4*)(out + (size_t)row * FFN + lane * 4) = ov;
}

// ---------------- MFMA GEMM: C[N,NC] = epi(A[N,K] @ W[NC,K]^T + bias) ----------------
// A is bf16 [N,K]; W is fp32 [NC,K] (converted to bf16 during LDS staging); bias fp32.
// EPI: 0 = none       -> bf16 out
//      1 = bias+gelu  -> bf16 out
//      2 = bias       -> fp32 out

template<int K, int NC, int EPI>
__global__ __launch_bounds__(256) void gemm_mfma(const u16* __restrict__ A, const float* __restrict__ W,
                                                 const float* __restrict__ bias, void* __restrict__ out, int N){
  constexpr int KP = K + 8;                 // +8 bf16 pad: breaks power-of-2 LDS bank stride
  __shared__ __align__(16) u16 As[64 * KP];
  __shared__ __align__(16) u16 Ws[64 * KP];
  const int tid = threadIdx.x;
  const int row0 = blockIdx.x * 64;
  const int n0 = blockIdx.y * 64;
  constexpr int CH = K / 8;                 // 16B bf16 chunks per A row
  for (int i = tid; i < 64 * CH; i += 256){
    int r = i / CH, c = (i - r * CH) * 8;
    int4 v = {0, 0, 0, 0};
    if (row0 + r < N) v = *(const int4*)(A + (size_t)(row0 + r) * K + c);
    *(int4*)(As + r * KP + c) = v;
  }
  constexpr int WCH = K / 4;                // float4 chunks per W row
  for (int i = tid; i < 64 * WCH; i += 256){
    int r = i / WCH, c = (i - r * WCH) * 4;
    float4 w = *(const float4*)(W + (size_t)(n0 + r) * K + c);
    ushort4 wv;
    wv.x = f2bf(w.x); wv.y = f2bf(w.y); wv.z = f2bf(w.z); wv.w = f2bf(w.w);
    *(ushort4*)(Ws + r * KP + c) = wv;
  }
  __syncthreads();
  const int lane = tid & 63, wv = tid >> 6;
  const int wm = wv >> 1, wn = wv & 1;     // 2x2 waves -> 64x64 block tile, 32x32 per wave
  const int l16 = lane & 15, quad = lane >> 4;
  f32x4 acc[2][2] = {};
  for (int ks = 0; ks < K; ks += 32){
    const int kb = ks + quad * 8;          // A/B frag: [idx = lane&15][k = quad*8 + j]
    bf16x8 a0 = *(const bf16x8*)(As + (wm * 32 + l16) * KP + kb);
    bf16x8 a1 = *(const bf16x8*)(As + (wm * 32 + 16 + l16) * KP + kb);
    bf16x8 b0 = *(const bf16x8*)(Ws + (wn * 32 + l16) * KP + kb);
    bf16x8 b1 = *(const bf16x8*)(Ws + (wn * 32 + 16 + l16) * KP + kb);
    acc[0][0] = __builtin_amdgcn_mfma_f32_16x16x32_bf16(a0, b0, acc[0][0], 0, 0, 0);
    acc[0][1] = __builtin_amdgcn_mfma_f32_16x16x32_bf16(a0, b1, acc[0][1], 0, 0, 0);
    acc[1][0] = __builtin_amdgcn_mfma_f32_16x16x32_bf16(a1, b0, acc[1][0], 0, 0, 0);
    acc[1][1] = __builtin_amdgcn_mfma_f32_16x16x32_bf16(a1, b1, acc[1][1], 0, 0, 0);
  }
  // C/D layout: col = lane&15, row = quad*4 + r
  for (int mi = 0; mi < 2; mi++)
  for (int ni = 0; ni < 2; ni++){
    const int col = n0 + wn * 32 + ni * 16 + l16;
    float bia = 0.f;
    if (EPI != 0) bia = bias[col];
    for (int r = 0; r < 4; r++){
      const int row = row0 + wm * 32 + mi * 16 + quad * 4 + r;
      if (row < N){
        float v = acc[mi][ni][r] + bia;
        if (EPI == 1) v = 0.5f * v * (1.f + erff(v * 0.70710678118654752f));
        if (EPI == 2) ((float*)out)[(size_t)row * NC + col] = v;
        else          ((u16*)out)[(size_t)row * NC + col] = f2bf(v);
      }
    }
  }
}

// ---------------- GCN aggregate + tanh gate ----------------
// out[d] = tanh( 2*dinv[d]^2*xw[d] + dinv[d]*sum_s dinv[s]*xw[s] + b_gcn ) * h[d]
// xw bf16 [N,256]; h bf16; dinv/b_gcn fp32; h3 bf16 out.

__global__ __launch_bounds__(256) void gcn_kernel(const u16* __restrict__ xw, const u16* __restrict__ h,
                                                  const float* __restrict__ dinv, const int* __restrict__ rp,
                                                  const int* __restrict__ ss, const float* __restrict__ b_gcn,
                                                  u16* __restrict__ h3, int N){
  int wv = threadIdx.x >> 6, lane = threadIdx.x & 63;
  int d = blockIdx.x * 4 + wv;
  if (d >= N) return;
  float dd = dinv[d];
  const ushort4 self = *(const ushort4*)(xw + (size_t)d * FFN + lane * 4);
  float ws = 2.f * dd * dd;
  float a0 = ws * bf2f(self.x), a1 = ws * bf2f(self.y), a2 = ws * bf2f(self.z), a3 = ws * bf2f(self.w);
  int s0 = rp[d], s1 = rp[d + 1];
  for (int i = s0; i < s1; i++){
    int s = ss[i];
    float w = dinv[s] * dd;
    const ushort4 v = *(const ushort4*)(xw + (size_t)s * FFN + lane * 4);
    a0 += w * bf2f(v.x); a1 += w * bf2f(v.y); a2 += w * bf2f(v.z); a3 += w * bf2f(v.w);
  }
  float4 bg = *(const float4*)(b_gcn + lane * 4);
  ushort4 hv = *(const ushort4*)(h + (size_t)d * FFN + lane * 4);
  ushort4 ov;
  ov.x = f2bf(tanhf(a0 + bg.x) * bf2f(hv.x));
  ov.y = f2bf(tanhf(a1 + bg.y) * bf2f(hv.y));
  ov.z = f2bf(tanhf(a2 + bg.z) * bf2f(hv.z));
  ov.w = f2bf(tanhf(a3 + bg.w) * bf2f(hv.w));
  *(ushort4*)(h3 + (size_t)d * FFN + lane * 4) = ov;
}

// ---------------- launch ----------------

extern "C" void kernel_launch(void* const* d_in, const int* in_sizes, int n_in,
                              void* d_out, int out_size, void* d_ws, size_t ws_size,
                              hipStream_t stream){
  const float* x     = (const float*)d_in[0];
  const int*   eidx  = (const int*)d_in[1];
  const float* ln1g  = (const float*)d_in[2];
  const float* ln1b  = (const float*)d_in[3];
  const float* w_in  = (const float*)d_in[4];
  const float* b_in  = (const float*)d_in[5];
  const float* ln2g  = (const float*)d_in[6];
  const float* ln2b  = (const float*)d_in[7];
  const float* w_gcn = (const float*)d_in[8];
  const float* b_gcn = (const float*)d_in[9];
  const float* w_out = (const float*)d_in[10];
  const float* b_out = (const float*)d_in[11];

  const int N = in_sizes[0] / HID;
  const int E = in_sizes[1] / 2;
  const int* src = eidx;
  const int* dst = eidx + E;

  char* ws = (char*)d_ws;
  size_t off = 0;
  auto alloc = [&](size_t bytes) -> char* {
    char* p = ws + off;
    off = (off + bytes + 255) & ~(size_t)255;
    return p;
  };
  u16*   xn   = (u16*)  alloc((size_t)N * HID * 2);
  u16*   h    = (u16*)  alloc((size_t)N * FFN * 2);
  u16*   g2n  = (u16*)  alloc((size_t)N * FFN * 2);
  u16*   xw   = (u16*)  alloc((size_t)N * FFN * 2);
  float* dinv = (float*)alloc((size_t)N * 4);
  int*   cnt  = (int*)  alloc((size_t)N * 4);
  int*   rp   = (int*)  alloc((size_t)(N + 1) * 4);
  int*   cur  = (int*)  alloc((size_t)N * 4);
  int*   ss   = (int*)  alloc((size_t)E * 4);
  const int NB = (N + 255) / 256;
  int*   part  = (int*) alloc((size_t)NB * 4);
  int*   parts = (int*) alloc((size_t)NB * 4);
  u16*   h3 = g2n;  // g2n dead once gemm2 produced xw; reuse for gated output

  hipMemsetAsync(cnt, 0, (size_t)N * 4, stream);
  hipMemsetAsync(cur, 0, (size_t)N * 4, stream);

  count_kernel<<<dim3((E + 255) / 256), dim3(256), 0, stream>>>(dst, cnt, E, N);
  dinv_kernel<<<dim3(NB), dim3(256), 0, stream>>>(cnt, dinv, N);
  scan1<<<dim3(NB), dim3(256), 0, stream>>>(cnt, part, N);
  scan2<<<dim3(1), dim3(64), 0, stream>>>(part, parts, rp, NB, N);
  scan3<<<dim3(NB), dim3(256), 0, stream>>>(cnt, parts, rp, N);
  scatter_kernel<<<dim3((E + 255) / 256), dim3(256), 0, stream>>>(src, dst, rp, cur, ss, E, N);

  ln1_kernel<<<dim3((N + 3) / 4), dim3(256), 0, stream>>>(x, ln1g, ln1b, xn, N);

  dim3 g1((N + 63) / 64, FFN / 64);
  gemm_mfma<HID, FFN, 1><<<g1, dim3(256), 0, stream>>>(xn, w_in, b_in, (void*)h, N);

  ln2_kernel<<<dim3((N + 3) / 4), dim3(256), 0, stream>>>(h, ln2g, ln2b, g2n, N);

  dim3 g2((N + 63) / 64, FFN / 64);
  gemm_mfma<FFN, FFN, 0><<<g2, dim3(256), 0, stream>>>(g2n, w_gcn, nullptr, (void*)xw, N);

  gcn_kernel<<<dim3((N + 3) / 4), dim3(256), 0, stream>>>(xw, h, dinv, rp, ss, b_gcn, h3, N);

  dim3 g3((N + 63) / 64, HID / 64);
  gemm_mfma<FFN, HID, 2><<<g3, dim3(256), 0, stream>>>(h3, w_out, b_out, d_out, N);
}

// Round 3
// 314.903 us; speedup vs baseline: 1.2144x; 1.2144x over previous
//
#include <hip/hip_runtime.h>
#include <hip/hip_bf16.h>

typedef unsigned short u16;
typedef short bf16x8 __attribute__((ext_vector_type(8)));
typedef float f32x4 __attribute__((ext_vector_type(4)));

#define HID 128
#define FFN 256

__device__ __forceinline__ float bf2f(u16 u){
  union { unsigned int i; float f; } v; v.i = ((unsigned int)u) << 16; return v.f;
}
__device__ __forceinline__ u16 f2bf(float f){
  union { float f; unsigned int i; } v; v.f = f;
  unsigned int x = v.i;
  unsigned int r = (x + 0x7fffu + ((x >> 16) & 1u)) >> 16;
  return (u16)r;
}

// ---------------- weight prep: fp32 -> bf16, one launch ----------------
// wb layout: [0,32768) w_in | [32768,98304) w_gcn | [98304,131072) w_out

__global__ __launch_bounds__(256) void prep_kernel(const float* __restrict__ w_in,
                                                   const float* __restrict__ w_gcn,
                                                   const float* __restrict__ w_out,
                                                   u16* __restrict__ wb){
  int i = blockIdx.x * 256 + threadIdx.x;
  if (i < 32768)       wb[i] = f2bf(w_in[i]);
  else if (i < 98304)  wb[i] = f2bf(w_gcn[i - 32768]);
  else if (i < 131072) wb[i] = f2bf(w_out[i - 98304]);
}

// ---------------- CSR build ----------------

__global__ __launch_bounds__(256) void count_kernel(const int* __restrict__ dst, int* __restrict__ cnt,
                                                    int E, int N){
  int e = blockIdx.x * 256 + threadIdx.x;
  if (e < E){
    int d = dst[e];
    if ((unsigned)d < (unsigned)N) atomicAdd(&cnt[d], 1);
  }
}

__global__ __launch_bounds__(256) void scan1(const int* __restrict__ cnt, int* __restrict__ part, int N){
  __shared__ int sm[256];
  int i = blockIdx.x * 256 + threadIdx.x;
  sm[threadIdx.x] = (i < N) ? cnt[i] : 0;
  __syncthreads();
  for (int o = 128; o; o >>= 1){
    if (threadIdx.x < o) sm[threadIdx.x] += sm[threadIdx.x + o];
    __syncthreads();
  }
  if (threadIdx.x == 0) part[blockIdx.x] = sm[0];
}

__global__ void scan2(const int* __restrict__ part, int* __restrict__ parts, int* __restrict__ rp,
                      int NB, int N){
  if (threadIdx.x == 0 && blockIdx.x == 0){
    int run = 0;
    for (int b = 0; b < NB; b++){ parts[b] = run; run += part[b]; }
    rp[N] = run;
  }
}

// scan3 also produces dinv (deg = cnt + 2 self-loop weight)
__global__ __launch_bounds__(256) void scan3(const int* __restrict__ cnt, const int* __restrict__ parts,
                                             int* __restrict__ rp, float* __restrict__ dinv, int N){
  __shared__ int sm[256];
  int t = threadIdx.x;
  int i = blockIdx.x * 256 + t;
  int v = (i < N) ? cnt[i] : 0;
  if (i < N) dinv[i] = rsqrtf((float)v + 2.0f);
  sm[t] = v;
  __syncthreads();
  for (int o = 1; o < 256; o <<= 1){
    int add = (t >= o) ? sm[t - o] : 0;
    __syncthreads();
    sm[t] += add;
    __syncthreads();
  }
  if (i < N) rp[i] = parts[blockIdx.x] + sm[t] - v;
}

// scatter edge -> (src, dinv[src]) packed int2, grouped by dst
__global__ __launch_bounds__(256) void scatter_kernel(const int* __restrict__ src, const int* __restrict__ dst,
                                                      const int* __restrict__ rp, int* __restrict__ cur,
                                                      const float* __restrict__ dinv,
                                                      int2* __restrict__ ssw, int E, int N){
  int e = blockIdx.x * 256 + threadIdx.x;
  if (e < E){
    int d = dst[e];
    if ((unsigned)d < (unsigned)N){
      int s = src[e];
      int p = atomicAdd(&cur[d], 1);
      int2 v; v.x = s; v.y = __float_as_int(dinv[s]);
      ssw[rp[d] + p] = v;
    }
  }
}

// ---------------- fused GEMM ----------------
// C[N,NC] = epi(LN?(A[N,K]) @ W[NC,K]^T + bias)
// Block: 64 rows x full NC (A staged once). W tiles 64 cols x 128 k at a time.
// MODE 1: A = fp32 x, LN1 in registers; epi = bias + gelu(exact) -> bf16
// MODE 2: A = bf16,   LN2 in LDS;       epi = none              -> bf16
// MODE 3: A = bf16,   no LN;            epi = bias              -> fp32

template<int K, int NC, int MODE>
__global__ __launch_bounds__(256) void gemm_fused(const void* __restrict__ Ap,
                                                  const float* __restrict__ lng, const float* __restrict__ lnb,
                                                  const u16* __restrict__ wb, const float* __restrict__ bias,
                                                  void* __restrict__ out, int N){
  constexpr int KP = K + 8;                  // row stride (elems); (K+8)*2B is 16B-multiple
  constexpr int KPW = 128 + 8;
  __shared__ __align__(16) u16 As[64 * KP];
  __shared__ __align__(16) u16 Ws[64 * KPW];
  const int tid = threadIdx.x;
  const int row0 = blockIdx.x * 64;

  if (MODE == 1){
    // ---- LN1 prologue: fp32 x [64,128] -> registers -> normalized bf16 LDS
    const int r = tid >> 2, p = tid & 3;     // 4 threads per row, 32 elems each
    const int row = row0 + r;
    float xr[32]; float s = 0.f, sq = 0.f;
    if (row < N){
      const float* xp = (const float*)Ap + (size_t)row * K + p * 32;
      #pragma unroll
      for (int j = 0; j < 8; j++){
        float4 v = *(const float4*)(xp + j * 4);
        xr[4*j] = v.x; xr[4*j+1] = v.y; xr[4*j+2] = v.z; xr[4*j+3] = v.w;
        s += v.x + v.y + v.z + v.w;
        sq += v.x*v.x + v.y*v.y + v.z*v.z + v.w*v.w;
      }
    }
    s  += __shfl_xor(s, 1, 64);  s  += __shfl_xor(s, 2, 64);
    sq += __shfl_xor(sq, 1, 64); sq += __shfl_xor(sq, 2, 64);
    float mu = s * (1.f / K);
    float rs = rsqrtf(sq * (1.f / K) - mu * mu + 1e-5f);
    u16* dp = As + r * KP + p * 32;
    if (row < N){
      #pragma unroll
      for (int j = 0; j < 8; j++){
        float4 gv = *(const float4*)(lng + p * 32 + j * 4);
        float4 bv = *(const float4*)(lnb + p * 32 + j * 4);
        ushort4 o;
        o.x = f2bf((xr[4*j  ] - mu) * rs * gv.x + bv.x);
        o.y = f2bf((xr[4*j+1] - mu) * rs * gv.y + bv.y);
        o.z = f2bf((xr[4*j+2] - mu) * rs * gv.z + bv.z);
        o.w = f2bf((xr[4*j+3] - mu) * rs * gv.w + bv.w);
        *(ushort4*)(dp + j * 4) = o;
      }
    } else {
      ushort4 z = {0, 0, 0, 0};
      #pragma unroll
      for (int j = 0; j < 8; j++) *(ushort4*)(dp + j * 4) = z;
    }
  } else {
    // ---- stage bf16 A [64,K]
    constexpr int CH = K / 8;
    for (int i = tid; i < 64 * CH; i += 256){
      int r = i / CH, c = (i - r * CH) * 8;
      int4 v = {0, 0, 0, 0};
      if (row0 + r < N) v = *(const int4*)((const u16*)Ap + (size_t)(row0 + r) * K + c);
      *(int4*)(As + r * KP + c) = v;
    }
    if (MODE == 2){
      __syncthreads();
      // ---- LN2 in LDS: 4 threads per row, 64 elems each
      const int r = tid >> 2, p = tid & 3;
      u16* rowp = As + r * KP + p * 64;
      float s = 0.f, sq = 0.f;
      #pragma unroll
      for (int j = 0; j < 8; j++){
        bf16x8 v8 = *(const bf16x8*)(rowp + j * 8);
        #pragma unroll
        for (int k = 0; k < 8; k++){ float f = bf2f((u16)v8[k]); s += f; sq += f * f; }
      }
      s  += __shfl_xor(s, 1, 64);  s  += __shfl_xor(s, 2, 64);
      sq += __shfl_xor(sq, 1, 64); sq += __shfl_xor(sq, 2, 64);
      float mu = s * (1.f / K);
      float rs = rsqrtf(sq * (1.f / K) - mu * mu + 1e-5f);
      #pragma unroll
      for (int j = 0; j < 8; j++){
        bf16x8 v8 = *(const bf16x8*)(rowp + j * 8);
        bf16x8 o8;
        #pragma unroll
        for (int k = 0; k < 8; k++){
          float g = lng[p * 64 + j * 8 + k];
          float b = lnb[p * 64 + j * 8 + k];
          o8[k] = (short)f2bf((bf2f((u16)v8[k]) - mu) * rs * g + b);
        }
        *(bf16x8*)(rowp + j * 8) = o8;
      }
    }
  }
  __syncthreads();

  const int lane = tid & 63, wvi = tid >> 6;
  const int wm = wvi >> 1, wn = wvi & 1;     // 2x2 waves over 64x64 output tile
  const int l16 = lane & 15, quad = lane >> 4;

  for (int ct = 0; ct < NC / 64; ct++){
    f32x4 acc[2][2] = {};
    for (int kh = 0; kh < K / 128; kh++){
      __syncthreads();                       // protect Ws from prior readers
      for (int i = tid; i < 64 * 16; i += 256){
        int r = i >> 4, c = (i & 15) * 8;
        *(int4*)(Ws + r * KPW + c) = *(const int4*)(wb + (size_t)(ct * 64 + r) * K + kh * 128 + c);
      }
      __syncthreads();
      #pragma unroll
      for (int ks = 0; ks < 128; ks += 32){
        const int ka = kh * 128 + ks + quad * 8;
        const int kb = ks + quad * 8;
        bf16x8 a0 = *(const bf16x8*)(As + (wm * 32 + l16) * KP + ka);
        bf16x8 a1 = *(const bf16x8*)(As + (wm * 32 + 16 + l16) * KP + ka);
        bf16x8 b0 = *(const bf16x8*)(Ws + (wn * 32 + l16) * KPW + kb);
        bf16x8 b1 = *(const bf16x8*)(Ws + (wn * 32 + 16 + l16) * KPW + kb);
        acc[0][0] = __builtin_amdgcn_mfma_f32_16x16x32_bf16(a0, b0, acc[0][0], 0, 0, 0);
        acc[0][1] = __builtin_amdgcn_mfma_f32_16x16x32_bf16(a0, b1, acc[0][1], 0, 0, 0);
        acc[1][0] = __builtin_amdgcn_mfma_f32_16x16x32_bf16(a1, b0, acc[1][0], 0, 0, 0);
        acc[1][1] = __builtin_amdgcn_mfma_f32_16x16x32_bf16(a1, b1, acc[1][1], 0, 0, 0);
      }
    }
    // ---- epilogue.  C/D: col = lane&15, row = quad*4 + r
    #pragma unroll
    for (int mi = 0; mi < 2; mi++)
    #pragma unroll
    for (int ni = 0; ni < 2; ni++){
      const int col = ct * 64 + wn * 32 + ni * 16 + l16;
      float bia = (MODE != 2) ? bias[col] : 0.f;
      #pragma unroll
      for (int r = 0; r < 4; r++){
        const int row = row0 + wm * 32 + mi * 16 + quad * 4 + r;
        if (row < N){
          float v = acc[mi][ni][r] + bia;
          if (MODE == 1) v = 0.5f * v * (1.f + erff(v * 0.70710678118654752f));
          if (MODE == 3) ((float*)out)[(size_t)row * NC + col] = v;
          else           ((u16*)out)[(size_t)row * NC + col] = f2bf(v);
        }
      }
    }
  }
}

// ---------------- GCN aggregate + tanh gate ----------------
// out[d] = tanh( 2*dinv[d]^2*xw[d] + dinv[d] * sum_s dinv[s]*xw[s] + b_gcn ) * h[d]

__global__ __launch_bounds__(256) void gcn_kernel(const u16* __restrict__ xw, const u16* __restrict__ h,
                                                  const float* __restrict__ dinv, const int* __restrict__ rp,
                                                  const int2* __restrict__ ssw, const float* __restrict__ b_gcn,
                                                  u16* __restrict__ h3, int N){
  int wvi = threadIdx.x >> 6, lane = threadIdx.x & 63;
  int d = blockIdx.x * 4 + wvi;
  if (d >= N) return;
  float dd = dinv[d];
  int s0 = rp[d], s1 = rp[d + 1];
  float a0 = 0.f, a1 = 0.f, a2 = 0.f, a3 = 0.f;
  int i = s0;
  for (; i + 4 <= s1; i += 4){
    int2 e0 = ssw[i], e1 = ssw[i + 1], e2 = ssw[i + 2], e3 = ssw[i + 3];
    const ushort4 v0 = *(const ushort4*)(xw + (size_t)e0.x * FFN + lane * 4);
    const ushort4 v1 = *(const ushort4*)(xw + (size_t)e1.x * FFN + lane * 4);
    const ushort4 v2 = *(const ushort4*)(xw + (size_t)e2.x * FFN + lane * 4);
    const ushort4 v3 = *(const ushort4*)(xw + (size_t)e3.x * FFN + lane * 4);
    float w0 = __int_as_float(e0.y), w1 = __int_as_float(e1.y);
    float w2 = __int_as_float(e2.y), w3 = __int_as_float(e3.y);
    a0 += w0 * bf2f(v0.x) + w1 * bf2f(v1.x) + w2 * bf2f(v2.x) + w3 * bf2f(v3.x);
    a1 += w0 * bf2f(v0.y) + w1 * bf2f(v1.y) + w2 * bf2f(v2.y) + w3 * bf2f(v3.y);
    a2 += w0 * bf2f(v0.z) + w1 * bf2f(v1.z) + w2 * bf2f(v2.z) + w3 * bf2f(v3.z);
    a3 += w0 * bf2f(v0.w) + w1 * bf2f(v1.w) + w2 * bf2f(v2.w) + w3 * bf2f(v3.w);
  }
  for (; i < s1; i++){
    int2 e = ssw[i];
    const ushort4 v = *(const ushort4*)(xw + (size_t)e.x * FFN + lane * 4);
    float w = __int_as_float(e.y);
    a0 += w * bf2f(v.x); a1 += w * bf2f(v.y); a2 += w * bf2f(v.z); a3 += w * bf2f(v.w);
  }
  const ushort4 sv = *(const ushort4*)(xw + (size_t)d * FFN + lane * 4);
  float ws = 2.f * dd * dd;
  a0 = dd * a0 + ws * bf2f(sv.x);
  a1 = dd * a1 + ws * bf2f(sv.y);
  a2 = dd * a2 + ws * bf2f(sv.z);
  a3 = dd * a3 + ws * bf2f(sv.w);
  float4 bg = *(const float4*)(b_gcn + lane * 4);
  ushort4 hv = *(const ushort4*)(h + (size_t)d * FFN + lane * 4);
  ushort4 ov;
  ov.x = f2bf(tanhf(a0 + bg.x) * bf2f(hv.x));
  ov.y = f2bf(tanhf(a1 + bg.y) * bf2f(hv.y));
  ov.z = f2bf(tanhf(a2 + bg.z) * bf2f(hv.z));
  ov.w = f2bf(tanhf(a3 + bg.w) * bf2f(hv.w));
  *(ushort4*)(h3 + (size_t)d * FFN + lane * 4) = ov;
}

// ---------------- launch ----------------

extern "C" void kernel_launch(void* const* d_in, const int* in_sizes, int n_in,
                              void* d_out, int out_size, void* d_ws, size_t ws_size,
                              hipStream_t stream){
  const float* x     = (const float*)d_in[0];
  const int*   eidx  = (const int*)d_in[1];
  const float* ln1g  = (const float*)d_in[2];
  const float* ln1b  = (const float*)d_in[3];
  const float* w_in  = (const float*)d_in[4];
  const float* b_in  = (const float*)d_in[5];
  const float* ln2g  = (const float*)d_in[6];
  const float* ln2b  = (const float*)d_in[7];
  const float* w_gcn = (const float*)d_in[8];
  const float* b_gcn = (const float*)d_in[9];
  const float* w_out = (const float*)d_in[10];
  const float* b_out = (const float*)d_in[11];

  const int N = in_sizes[0] / HID;
  const int E = in_sizes[1] / 2;
  const int* src = eidx;
  const int* dst = eidx + E;

  char* ws = (char*)d_ws;
  size_t off = 0;
  auto alloc = [&](size_t bytes) -> char* {
    char* p = ws + off;
    off = (off + bytes + 255) & ~(size_t)255;
    return p;
  };
  u16*   h    = (u16*)  alloc((size_t)N * FFN * 2);
  u16*   xw   = (u16*)  alloc((size_t)N * FFN * 2);
  u16*   h3   = (u16*)  alloc((size_t)N * FFN * 2);
  float* dinv = (float*)alloc((size_t)N * 4);
  int*   cnt  = (int*)  alloc((size_t)N * 4);
  int*   rp   = (int*)  alloc((size_t)(N + 1) * 4);
  int*   cur  = (int*)  alloc((size_t)N * 4);
  int2*  ssw  = (int2*) alloc((size_t)E * 8);
  const int NB = (N + 255) / 256;
  int*   part  = (int*) alloc((size_t)NB * 4);
  int*   parts = (int*) alloc((size_t)NB * 4);
  u16*   wb    = (u16*) alloc((size_t)131072 * 2);
  u16*   wb_in  = wb;
  u16*   wb_gcn = wb + 32768;
  u16*   wb_out = wb + 98304;

  hipMemsetAsync(cnt, 0, (size_t)N * 4, stream);
  hipMemsetAsync(cur, 0, (size_t)N * 4, stream);

  prep_kernel<<<dim3(512), dim3(256), 0, stream>>>(w_in, w_gcn, w_out, wb);
  count_kernel<<<dim3((E + 255) / 256), dim3(256), 0, stream>>>(dst, cnt, E, N);
  scan1<<<dim3(NB), dim3(256), 0, stream>>>(cnt, part, N);
  scan2<<<dim3(1), dim3(64), 0, stream>>>(part, parts, rp, NB, N);
  scan3<<<dim3(NB), dim3(256), 0, stream>>>(cnt, parts, rp, dinv, N);
  scatter_kernel<<<dim3((E + 255) / 256), dim3(256), 0, stream>>>(src, dst, rp, cur, dinv, ssw, E, N);

  const int RB = (N + 63) / 64;
  gemm_fused<HID, FFN, 1><<<dim3(RB), dim3(256), 0, stream>>>(x,  ln1g, ln1b, wb_in,  b_in,  (void*)h,  N);
  gemm_fused<FFN, FFN, 2><<<dim3(RB), dim3(256), 0, stream>>>(h,  ln2g, ln2b, wb_gcn, nullptr, (void*)xw, N);
  gcn_kernel<<<dim3((N + 3) / 4), dim3(256), 0, stream>>>(xw, h, dinv, rp, ssw, b_gcn, h3, N);
  gemm_fused<FFN, HID, 3><<<dim3(RB), dim3(256), 0, stream>>>(h3, nullptr, nullptr, wb_out, b_out, d_out, N);
}

// Round 5
// 310.112 us; speedup vs baseline: 1.2331x; 1.0154x over previous
//
#include <hip/hip_runtime.h>
#include <hip/hip_bf16.h>

typedef unsigned short u16;
typedef short bf16x8 __attribute__((ext_vector_type(8)));
typedef float f32x4 __attribute__((ext_vector_type(4)));

#define HID 128
#define FFN 256

__device__ __forceinline__ float bf2f(u16 u){
  union { unsigned int i; float f; } v; v.i = ((unsigned int)u) << 16; return v.f;
}
__device__ __forceinline__ u16 f2bf(float f){
  union { float f; unsigned int i; } v; v.f = f;
  unsigned int x = v.i;
  unsigned int r = (x + 0x7fffu + ((x >> 16) & 1u)) >> 16;
  return (u16)r;
}

// ---------------- weight prep: fp32 -> bf16, one launch ----------------
// wb layout: [0,32768) w_in | [32768,98304) w_gcn | [98304,131072) w_out

__global__ __launch_bounds__(256) void prep_kernel(const float* __restrict__ w_in,
                                                   const float* __restrict__ w_gcn,
                                                   const float* __restrict__ w_out,
                                                   u16* __restrict__ wb){
  int i = blockIdx.x * 256 + threadIdx.x;
  if (i < 32768)       wb[i] = f2bf(w_in[i]);
  else if (i < 98304)  wb[i] = f2bf(w_gcn[i - 32768]);
  else if (i < 131072) wb[i] = f2bf(w_out[i - 98304]);
}

// ---------------- CSR build ----------------

__global__ __launch_bounds__(256) void count_kernel(const int* __restrict__ dst, int* __restrict__ cnt,
                                                    int E, int N){
  int e = blockIdx.x * 256 + threadIdx.x;
  if (e < E){
    int d = dst[e];
    if ((unsigned)d < (unsigned)N) atomicAdd(&cnt[d], 1);
  }
}

__global__ __launch_bounds__(256) void scan1(const int* __restrict__ cnt, int* __restrict__ part, int N){
  __shared__ int sm[256];
  int i = blockIdx.x * 256 + threadIdx.x;
  sm[threadIdx.x] = (i < N) ? cnt[i] : 0;
  __syncthreads();
  for (int o = 128; o; o >>= 1){
    if (threadIdx.x < o) sm[threadIdx.x] += sm[threadIdx.x + o];
    __syncthreads();
  }
  if (threadIdx.x == 0) part[blockIdx.x] = sm[0];
}

// parallel single-block exclusive scan over NB block sums (NB <= 256)
__global__ __launch_bounds__(256) void scan2(const int* __restrict__ part, int* __restrict__ parts,
                                             int* __restrict__ rp, int NB, int N){
  __shared__ int sm[256];
  int t = threadIdx.x;
  int v = (t < NB) ? part[t] : 0;
  sm[t] = v;
  __syncthreads();
  for (int o = 1; o < 256; o <<= 1){
    int a = (t >= o) ? sm[t - o] : 0;
    __syncthreads();
    sm[t] += a;
    __syncthreads();
  }
  if (t < NB) parts[t] = sm[t] - v;
  if (t == 0) rp[N] = sm[255];
}

// scan3 also produces dinv (deg = cnt + 2 self-loop weight)
__global__ __launch_bounds__(256) void scan3(const int* __restrict__ cnt, const int* __restrict__ parts,
                                             int* __restrict__ rp, float* __restrict__ dinv, int N){
  __shared__ int sm[256];
  int t = threadIdx.x;
  int i = blockIdx.x * 256 + t;
  int v = (i < N) ? cnt[i] : 0;
  if (i < N) dinv[i] = rsqrtf((float)v + 2.0f);
  sm[t] = v;
  __syncthreads();
  for (int o = 1; o < 256; o <<= 1){
    int add = (t >= o) ? sm[t - o] : 0;
    __syncthreads();
    sm[t] += add;
    __syncthreads();
  }
  if (i < N) rp[i] = parts[blockIdx.x] + sm[t] - v;
}

// scatter edge -> (src, dinv[src]) packed int2, grouped by dst
__global__ __launch_bounds__(256) void scatter_kernel(const int* __restrict__ src, const int* __restrict__ dst,
                                                      const int* __restrict__ rp, int* __restrict__ cur,
                                                      const float* __restrict__ dinv,
                                                      int2* __restrict__ ssw, int E, int N){
  int e = blockIdx.x * 256 + threadIdx.x;
  if (e < E){
    int d = dst[e];
    if ((unsigned)d < (unsigned)N){
      int s = src[e];
      int p = atomicAdd(&cur[d], 1);
      int2 v; v.x = s; v.y = __float_as_int(dinv[s]);
      ssw[rp[d] + p] = v;
    }
  }
}

// ---------------- fused GEMM ----------------
// C[N,NC] = epi(LN?(A[N,K]) @ W[NC,K]^T + bias)
// Block: 64 rows x full NC (A staged once). W tiles 64 cols x 128 k at a time.
// Epilogue: acc -> LDS C-tile (reuses Ws) -> coalesced vector stores.
// MODE 1: A = fp32 x, LN1 in registers; epi = bias + gelu(exact) -> bf16
// MODE 2: A = bf16,   LN2 in LDS;       epi = none              -> bf16
// MODE 3: A = bf16,   no LN;            epi = bias              -> fp32

template<int K, int NC, int MODE>
__global__ __launch_bounds__(256) void gemm_fused(const void* __restrict__ Ap,
                                                  const float* __restrict__ lng, const float* __restrict__ lnb,
                                                  const u16* __restrict__ wb, const float* __restrict__ bias,
                                                  void* __restrict__ out, int N){
  constexpr int KP = K + 8;                  // row stride (elems); (K+8)*2B is 16B-multiple
  constexpr int KPW = 128 + 8;
  __shared__ __align__(16) u16 As[64 * KP];
  __shared__ __align__(16) u16 Ws[64 * KPW]; // 17408 B; also reused as C-tile (fp32 64x68 = 17408 B exact)
  const int tid = threadIdx.x;
  const int row0 = blockIdx.x * 64;

  if (MODE == 1){
    // ---- LN1 prologue: fp32 x [64,128] -> registers -> normalized bf16 LDS
    const int r = tid >> 2, p = tid & 3;     // 4 threads per row, 32 elems each
    const int row = row0 + r;
    float xr[32]; float s = 0.f, sq = 0.f;
    if (row < N){
      const float* xp = (const float*)Ap + (size_t)row * K + p * 32;
      #pragma unroll
      for (int j = 0; j < 8; j++){
        float4 v = *(const float4*)(xp + j * 4);
        xr[4*j] = v.x; xr[4*j+1] = v.y; xr[4*j+2] = v.z; xr[4*j+3] = v.w;
        s += v.x + v.y + v.z + v.w;
        sq += v.x*v.x + v.y*v.y + v.z*v.z + v.w*v.w;
      }
    }
    s  += __shfl_xor(s, 1, 64);  s  += __shfl_xor(s, 2, 64);
    sq += __shfl_xor(sq, 1, 64); sq += __shfl_xor(sq, 2, 64);
    float mu = s * (1.f / K);
    float rs = rsqrtf(sq * (1.f / K) - mu * mu + 1e-5f);
    u16* dp = As + r * KP + p * 32;
    if (row < N){
      #pragma unroll
      for (int j = 0; j < 8; j++){
        float4 gv = *(const float4*)(lng + p * 32 + j * 4);
        float4 bv = *(const float4*)(lnb + p * 32 + j * 4);
        ushort4 o;
        o.x = f2bf((xr[4*j  ] - mu) * rs * gv.x + bv.x);
        o.y = f2bf((xr[4*j+1] - mu) * rs * gv.y + bv.y);
        o.z = f2bf((xr[4*j+2] - mu) * rs * gv.z + bv.z);
        o.w = f2bf((xr[4*j+3] - mu) * rs * gv.w + bv.w);
        *(ushort4*)(dp + j * 4) = o;
      }
    } else {
      ushort4 z = {0, 0, 0, 0};
      #pragma unroll
      for (int j = 0; j < 8; j++) *(ushort4*)(dp + j * 4) = z;
    }
  } else {
    // ---- stage bf16 A [64,K]
    constexpr int CH = K / 8;
    for (int i = tid; i < 64 * CH; i += 256){
      int r = i / CH, c = (i - r * CH) * 8;
      int4 v = {0, 0, 0, 0};
      if (row0 + r < N) v = *(const int4*)((const u16*)Ap + (size_t)(row0 + r) * K + c);
      *(int4*)(As + r * KP + c) = v;
    }
    if (MODE == 2){
      __syncthreads();
      // ---- LN2 in LDS: 4 threads per row, 64 elems each
      const int r = tid >> 2, p = tid & 3;
      u16* rowp = As + r * KP + p * 64;
      float s = 0.f, sq = 0.f;
      #pragma unroll
      for (int j = 0; j < 8; j++){
        bf16x8 v8 = *(const bf16x8*)(rowp + j * 8);
        #pragma unroll
        for (int k = 0; k < 8; k++){ float f = bf2f((u16)v8[k]); s += f; sq += f * f; }
      }
      s  += __shfl_xor(s, 1, 64);  s  += __shfl_xor(s, 2, 64);
      sq += __shfl_xor(sq, 1, 64); sq += __shfl_xor(sq, 2, 64);
      float mu = s * (1.f / K);
      float rs = rsqrtf(sq * (1.f / K) - mu * mu + 1e-5f);
      #pragma unroll
      for (int j = 0; j < 8; j++){
        bf16x8 v8 = *(const bf16x8*)(rowp + j * 8);
        float4 g0 = *(const float4*)(lng + p * 64 + j * 8);
        float4 g1 = *(const float4*)(lng + p * 64 + j * 8 + 4);
        float4 b0 = *(const float4*)(lnb + p * 64 + j * 8);
        float4 b1 = *(const float4*)(lnb + p * 64 + j * 8 + 4);
        bf16x8 o8;
        o8[0] = (short)f2bf((bf2f((u16)v8[0]) - mu) * rs * g0.x + b0.x);
        o8[1] = (short)f2bf((bf2f((u16)v8[1]) - mu) * rs * g0.y + b0.y);
        o8[2] = (short)f2bf((bf2f((u16)v8[2]) - mu) * rs * g0.z + b0.z);
        o8[3] = (short)f2bf((bf2f((u16)v8[3]) - mu) * rs * g0.w + b0.w);
        o8[4] = (short)f2bf((bf2f((u16)v8[4]) - mu) * rs * g1.x + b1.x);
        o8[5] = (short)f2bf((bf2f((u16)v8[5]) - mu) * rs * g1.y + b1.y);
        o8[6] = (short)f2bf((bf2f((u16)v8[6]) - mu) * rs * g1.z + b1.z);
        o8[7] = (short)f2bf((bf2f((u16)v8[7]) - mu) * rs * g1.w + b1.w);
        *(bf16x8*)(rowp + j * 8) = o8;
      }
    }
  }
  __syncthreads();

  const int lane = tid & 63, wvi = tid >> 6;
  const int wm = wvi >> 1, wn = wvi & 1;     // 2x2 waves over 64x64 output tile
  const int l16 = lane & 15, quad = lane >> 4;

  for (int ct = 0; ct < NC / 64; ct++){
    f32x4 acc[2][2] = {};
    for (int kh = 0; kh < K / 128; kh++){
      __syncthreads();                       // protect Ws (stage target / C-tile) from prior readers
      for (int i = tid; i < 64 * 16; i += 256){
        int r = i >> 4, c = (i & 15) * 8;
        *(int4*)(Ws + r * KPW + c) = *(const int4*)(wb + (size_t)(ct * 64 + r) * K + kh * 128 + c);
      }
      __syncthreads();
      #pragma unroll
      for (int ks = 0; ks < 128; ks += 32){
        const int ka = kh * 128 + ks + quad * 8;
        const int kb = ks + quad * 8;
        bf16x8 a0 = *(const bf16x8*)(As + (wm * 32 + l16) * KP + ka);
        bf16x8 a1 = *(const bf16x8*)(As + (wm * 32 + 16 + l16) * KP + ka);
        bf16x8 b0 = *(const bf16x8*)(Ws + (wn * 32 + l16) * KPW + kb);
        bf16x8 b1 = *(const bf16x8*)(Ws + (wn * 32 + 16 + l16) * KPW + kb);
        acc[0][0] = __builtin_amdgcn_mfma_f32_16x16x32_bf16(a0, b0, acc[0][0], 0, 0, 0);
        acc[0][1] = __builtin_amdgcn_mfma_f32_16x16x32_bf16(a0, b1, acc[0][1], 0, 0, 0);
        acc[1][0] = __builtin_amdgcn_mfma_f32_16x16x32_bf16(a1, b0, acc[1][0], 0, 0, 0);
        acc[1][1] = __builtin_amdgcn_mfma_f32_16x16x32_bf16(a1, b1, acc[1][1], 0, 0, 0);
      }
    }
    // ---- epilogue: acc -> LDS C-tile (Ws reuse), then coalesced stores ----
    __syncthreads();                         // all waves done reading Ws for this ct
    if (MODE == 3){
      float* Ct = (float*)Ws;                // [64][68]
      #pragma unroll
      for (int mi = 0; mi < 2; mi++)
      #pragma unroll
      for (int ni = 0; ni < 2; ni++){
        const int cl = wn * 32 + ni * 16 + l16;
        const float bia = bias[ct * 64 + cl];
        #pragma unroll
        for (int r = 0; r < 4; r++){
          const int rl = wm * 32 + mi * 16 + quad * 4 + r;
          Ct[rl * 68 + cl] = acc[mi][ni][r] + bia;
        }
      }
    } else {
      u16* Ct = Ws;                          // [64][72]
      #pragma unroll
      for (int mi = 0; mi < 2; mi++)
      #pragma unroll
      for (int ni = 0; ni < 2; ni++){
        const int cl = wn * 32 + ni * 16 + l16;
        const float bia = (MODE == 1) ? bias[ct * 64 + cl] : 0.f;
        #pragma unroll
        for (int r = 0; r < 4; r++){
          const int rl = wm * 32 + mi * 16 + quad * 4 + r;
          float v = acc[mi][ni][r] + bia;
          if (MODE == 1) v = 0.5f * v * (1.f + erff(v * 0.70710678118654752f));
          Ct[rl * 72 + cl] = f2bf(v);
        }
      }
    }
    __syncthreads();
    {
      const int rl = tid >> 2, seg = tid & 3;  // 4 threads per row, 16 cols each
      const int grow = row0 + rl;
      if (grow < N){
        if (MODE == 3){
          const float* s = (const float*)Ws + rl * 68 + seg * 16;
          float* dst = (float*)out + (size_t)grow * NC + ct * 64 + seg * 16;
          #pragma unroll
          for (int j = 0; j < 4; j++) *(float4*)(dst + j * 4) = *(const float4*)(s + j * 4);
        } else {
          const u16* s = Ws + rl * 72 + seg * 16;
          u16* dst = (u16*)out + (size_t)grow * NC + ct * 64 + seg * 16;
          *(int4*)dst       = *(const int4*)s;
          *(int4*)(dst + 8) = *(const int4*)(s + 8);
        }
      }
    }
  }
}

// ---------------- GCN aggregate + tanh gate ----------------
// out[d] = tanh( 2*dinv[d]^2*xw[d] + dinv[d] * sum_s dinv[s]*xw[s] + b_gcn ) * h[d]

__global__ __launch_bounds__(256) void gcn_kernel(const u16* __restrict__ xw, const u16* __restrict__ h,
                                                  const float* __restrict__ dinv, const int* __restrict__ rp,
                                                  const int2* __restrict__ ssw, const float* __restrict__ b_gcn,
                                                  u16* __restrict__ h3, int N){
  int wvi = threadIdx.x >> 6, lane = threadIdx.x & 63;
  int d = blockIdx.x * 4 + wvi;
  if (d >= N) return;
  float dd = dinv[d];
  int s0 = rp[d], s1 = rp[d + 1];
  float a0 = 0.f, a1 = 0.f, a2 = 0.f, a3 = 0.f;
  int i = s0;
  for (; i + 4 <= s1; i += 4){
    int2 e0 = ssw[i], e1 = ssw[i + 1], e2 = ssw[i + 2], e3 = ssw[i + 3];
    const ushort4 v0 = *(const ushort4*)(xw + (size_t)e0.x * FFN + lane * 4);
    const ushort4 v1 = *(const ushort4*)(xw + (size_t)e1.x * FFN + lane * 4);
    const ushort4 v2 = *(const ushort4*)(xw + (size_t)e2.x * FFN + lane * 4);
    const ushort4 v3 = *(const ushort4*)(xw + (size_t)e3.x * FFN + lane * 4);
    float w0 = __int_as_float(e0.y), w1 = __int_as_float(e1.y);
    float w2 = __int_as_float(e2.y), w3 = __int_as_float(e3.y);
    a0 += w0 * bf2f(v0.x) + w1 * bf2f(v1.x) + w2 * bf2f(v2.x) + w3 * bf2f(v3.x);
    a1 += w0 * bf2f(v0.y) + w1 * bf2f(v1.y) + w2 * bf2f(v2.y) + w3 * bf2f(v3.y);
    a2 += w0 * bf2f(v0.z) + w1 * bf2f(v1.z) + w2 * bf2f(v2.z) + w3 * bf2f(v3.z);
    a3 += w0 * bf2f(v0.w) + w1 * bf2f(v1.w) + w2 * bf2f(v2.w) + w3 * bf2f(v3.w);
  }
  for (; i < s1; i++){
    int2 e = ssw[i];
    const ushort4 v = *(const ushort4*)(xw + (size_t)e.x * FFN + lane * 4);
    float w = __int_as_float(e.y);
    a0 += w * bf2f(v.x); a1 += w * bf2f(v.y); a2 += w * bf2f(v.z); a3 += w * bf2f(v.w);
  }
  const ushort4 sv = *(const ushort4*)(xw + (size_t)d * FFN + lane * 4);
  float ws = 2.f * dd * dd;
  a0 = dd * a0 + ws * bf2f(sv.x);
  a1 = dd * a1 + ws * bf2f(sv.y);
  a2 = dd * a2 + ws * bf2f(sv.z);
  a3 = dd * a3 + ws * bf2f(sv.w);
  float4 bg = *(const float4*)(b_gcn + lane * 4);
  ushort4 hv = *(const ushort4*)(h + (size_t)d * FFN + lane * 4);
  ushort4 ov;
  ov.x = f2bf(tanhf(a0 + bg.x) * bf2f(hv.x));
  ov.y = f2bf(tanhf(a1 + bg.y) * bf2f(hv.y));
  ov.z = f2bf(tanhf(a2 + bg.z) * bf2f(hv.z));
  ov.w = f2bf(tanhf(a3 + bg.w) * bf2f(hv.w));
  *(ushort4*)(h3 + (size_t)d * FFN + lane * 4) = ov;
}

// ---------------- launch ----------------

extern "C" void kernel_launch(void* const* d_in, const int* in_sizes, int n_in,
                              void* d_out, int out_size, void* d_ws, size_t ws_size,
                              hipStream_t stream){
  const float* x     = (const float*)d_in[0];
  const int*   eidx  = (const int*)d_in[1];
  const float* ln1g  = (const float*)d_in[2];
  const float* ln1b  = (const float*)d_in[3];
  const float* w_in  = (const float*)d_in[4];
  const float* b_in  = (const float*)d_in[5];
  const float* ln2g  = (const float*)d_in[6];
  const float* ln2b  = (const float*)d_in[7];
  const float* w_gcn = (const float*)d_in[8];
  const float* b_gcn = (const float*)d_in[9];
  const float* w_out = (const float*)d_in[10];
  const float* b_out = (const float*)d_in[11];

  const int N = in_sizes[0] / HID;
  const int E = in_sizes[1] / 2;
  const int* src = eidx;
  const int* dst = eidx + E;

  char* ws = (char*)d_ws;
  size_t off = 0;
  auto alloc = [&](size_t bytes) -> char* {
    char* p = ws + off;
    off = (off + bytes + 255) & ~(size_t)255;
    return p;
  };
  u16*   h    = (u16*)  alloc((size_t)N * FFN * 2);
  u16*   xw   = (u16*)  alloc((size_t)N * FFN * 2);
  u16*   h3   = (u16*)  alloc((size_t)N * FFN * 2);
  float* dinv = (float*)alloc((size_t)N * 4);
  int*   cnt  = (int*)  alloc((size_t)N * 4);
  int*   rp   = (int*)  alloc((size_t)(N + 1) * 4);
  int*   cur  = (int*)  alloc((size_t)N * 4);
  int2*  ssw  = (int2*) alloc((size_t)E * 8);
  const int NB = (N + 255) / 256;
  int*   part  = (int*) alloc((size_t)NB * 4);
  int*   parts = (int*) alloc((size_t)NB * 4);
  u16*   wb    = (u16*) alloc((size_t)131072 * 2);
  u16*   wb_in  = wb;
  u16*   wb_gcn = wb + 32768;
  u16*   wb_out = wb + 98304;

  hipMemsetAsync(cnt, 0, (size_t)N * 4, stream);
  hipMemsetAsync(cur, 0, (size_t)N * 4, stream);

  prep_kernel<<<dim3(512), dim3(256), 0, stream>>>(w_in, w_gcn, w_out, wb);
  count_kernel<<<dim3((E + 255) / 256), dim3(256), 0, stream>>>(dst, cnt, E, N);
  scan1<<<dim3(NB), dim3(256), 0, stream>>>(cnt, part, N);
  scan2<<<dim3(1), dim3(256), 0, stream>>>(part, parts, rp, NB, N);
  scan3<<<dim3(NB), dim3(256), 0, stream>>>(cnt, parts, rp, dinv, N);
  scatter_kernel<<<dim3((E + 255) / 256), dim3(256), 0, stream>>>(src, dst, rp, cur, dinv, ssw, E, N);

  const int RB = (N + 63) / 64;
  gemm_fused<HID, FFN, 1><<<dim3(RB), dim3(256), 0, stream>>>(x,  ln1g, ln1b, wb_in,  b_in,   (void*)h,  N);
  gemm_fused<FFN, FFN, 2><<<dim3(RB), dim3(256), 0, stream>>>(h,  ln2g, ln2b, wb_gcn, nullptr, (void*)xw, N);
  gcn_kernel<<<dim3((N + 3) / 4), dim3(256), 0, stream>>>(xw, h, dinv, rp, ssw, b_gcn, h3, N);
  gemm_fused<FFN, HID, 3><<<dim3(RB), dim3(256), 0, stream>>>(h3, nullptr, nullptr, wb_out, b_out, d_out, N);
}